// Round 7
// baseline (1150.471 us; speedup 1.0000x reference)
//
#include <hip/hip_runtime.h>
#include <hip/hip_bf16.h>

#define BB 64
#define TT 512
#define FF 1024
#define KK 64

// ---------------- Emission GEMM (round-1 version, measured ~83-88us, 4x) ----------------
#define BM 64
#define BF 64
#define LDA 68  // padded LDS stride: 272 B rows, 16B-aligned, breaks pow-2 bank conflicts

__global__ __launch_bounds__(256)
void emission_kernel(const float* __restrict__ X, const float* __restrict__ W,
                     const float* __restrict__ bias, float* __restrict__ em)
{
    __shared__ float As[BF][LDA];   // As[f][m]  (transposed)
    __shared__ float Bs[BF][LDA];   // Bs[f][k]  (transposed)
    const int tid = threadIdx.x;
    const int row0 = blockIdx.x * BM;
    const int tm = tid & 15;
    const int tn = tid >> 4;
    const int lq = tid & 15;
    const int lr = tid >> 4;

    float acc[4][4];
#pragma unroll
    for (int i = 0; i < 4; ++i)
#pragma unroll
        for (int jj = 0; jj < 4; ++jj) acc[i][jj] = 0.f;

    for (int f0 = 0; f0 < FF; f0 += BF) {
#pragma unroll
        for (int p = 0; p < 4; ++p) {
            const int r = p * 16 + lr;
            float4 a = *(const float4*)(X + (size_t)(row0 + r) * FF + f0 + lq * 4);
            As[lq * 4 + 0][r] = a.x;
            As[lq * 4 + 1][r] = a.y;
            As[lq * 4 + 2][r] = a.z;
            As[lq * 4 + 3][r] = a.w;
            float4 w = *(const float4*)(W + (size_t)r * FF + f0 + lq * 4);
            Bs[lq * 4 + 0][r] = w.x;
            Bs[lq * 4 + 1][r] = w.y;
            Bs[lq * 4 + 2][r] = w.z;
            Bs[lq * 4 + 3][r] = w.w;
        }
        __syncthreads();
#pragma unroll
        for (int f = 0; f < BF; ++f) {
            float4 a = *(const float4*)&As[f][tm * 4];
            float4 b = *(const float4*)&Bs[f][tn * 4];
            acc[0][0] += a.x * b.x; acc[0][1] += a.x * b.y; acc[0][2] += a.x * b.z; acc[0][3] += a.x * b.w;
            acc[1][0] += a.y * b.x; acc[1][1] += a.y * b.y; acc[1][2] += a.y * b.z; acc[1][3] += a.y * b.w;
            acc[2][0] += a.z * b.x; acc[2][1] += a.z * b.y; acc[2][2] += a.z * b.z; acc[2][3] += a.z * b.w;
            acc[3][0] += a.w * b.x; acc[3][1] += a.w * b.y; acc[3][2] += a.w * b.z; acc[3][3] += a.w * b.w;
        }
        __syncthreads();
    }

    const float4 b4 = *(const float4*)(bias + tn * 4);
#pragma unroll
    for (int i = 0; i < 4; ++i) {
        float4 o;
        o.x = acc[i][0] + b4.x;
        o.y = acc[i][1] + b4.y;
        o.z = acc[i][2] + b4.z;
        o.w = acc[i][3] + b4.w;
        *(float4*)(em + (size_t)(row0 + tm * 4 + i) * KK + tn * 4) = o;
    }
}

// ---------------- Viterbi ----------------
// Forward: ONE wave, lane j = next tag. Per step:
//   1) score broadcast via LDS: one ds_write_b32 + 16 uniform-address
//      ds_read_b128 (same addr on all lanes = hardware broadcast, conflict-free).
//      No readlane -> no VALU-writes-SGPR RAW hazard (r6 suspect b).
//   2) all-VGPR candidate math: v_i = (s_i + tc_i) + e  (reference order).
//   3) 63-node contiguous-pair tournament, left-wins-on->= = first-index
//      argmax (semantics validated r3-r5). No loop-carried select chain
//      (r6 suspect a).
// trans column in 16 float4 with compile-time component indices only
// (register-promotion-safe). No barriers in hot loop.
// Backtrack: 4-wave 8-segment hypothesis replay (validated r2-r6).
__global__ __launch_bounds__(256)
void viterbi_kernel(const float* __restrict__ em, const void* __restrict__ maskp,
                    const float* __restrict__ startT, const float* __restrict__ endT,
                    const float* __restrict__ trans, float* __restrict__ pred)
{
    const int b = blockIdx.x;
    const int tid = threadIdx.x;
    const int w = tid >> 6;
    const int j = tid & 63;

    __shared__ unsigned char hist[TT][KK];     // 32 KB
    __shared__ unsigned char hypo[8][64][64];  // 32 KB
    __shared__ float sbuf[KK];                 // score broadcast buffer
    __shared__ int bt_sh;

    // mask layout detection (lengths >= 256 so mask[0][1] is true):
    const unsigned char* m8 = (const unsigned char*)maskp;
    const int* m32 = (const int*)maskp;
    const bool u8m = (m8[1] != 0);

    if (w == 0) {
        // trans column j as 16 float4, constant component indices after unroll
        float4 tcv[16];
#pragma unroll
        for (int c = 0; c < 16; ++c) {
            tcv[c].x = trans[(c * 4 + 0) * KK + j];
            tcv[c].y = trans[(c * 4 + 1) * KK + j];
            tcv[c].z = trans[(c * 4 + 2) * KK + j];
            tcv[c].w = trans[(c * 4 + 3) * KK + j];
        }

        const float* emb = em + (size_t)b * TT * KK;
        float score = startT[j] + emb[j];   // t = 0
        const float endv = endT[j];

        float e_cur = emb[KK + j];          // prefetch t = 1
        int   m_cur = u8m ? (int)m8[b * TT + 1] : m32[b * TT + 1];

        int t = 1;
        for (; t < TT; ++t) {
            const int tn2 = (t + 1 < TT) ? (t + 1) : (TT - 1);
            const float e_next = emb[(size_t)tn2 * KK + j];          // prefetch t+1
            const int   m_next = u8m ? (int)m8[b * TT + tn2] : m32[b * TT + tn2];

            if (!m_cur) break;   // length mask: monotone

            // --- broadcast scores (single wave: no barrier, compiler inserts lgkmcnt)
            sbuf[j] = score;
            float4 sc[16];
#pragma unroll
            for (int c = 0; c < 16; ++c) sc[c] = *(const float4*)&sbuf[c * 4];

            // --- 64 candidates + depth-2 chunk trees
            float cw[16]; int ci[16];
#pragma unroll
            for (int c = 0; c < 16; ++c) {
                const float v0 = (sc[c].x + tcv[c].x) + e_cur;   // reference order
                const float v1 = (sc[c].y + tcv[c].y) + e_cur;
                const float v2 = (sc[c].z + tcv[c].z) + e_cur;
                const float v3 = (sc[c].w + tcv[c].w) + e_cur;
                const bool a01 = v0 >= v1;
                const float w01 = a01 ? v0 : v1;
                const int   i01 = a01 ? (4 * c + 0) : (4 * c + 1);
                const bool a23 = v2 >= v3;
                const float w23 = a23 ? v2 : v3;
                const int   i23 = a23 ? (4 * c + 2) : (4 * c + 3);
                const bool af = w01 >= w23;
                cw[c] = af ? w01 : w23;
                ci[c] = af ? i01 : i23;
            }
            // --- 16 -> 1 contiguous-pair tree (left-wins => first index)
#pragma unroll
            for (int n = 8; n >= 1; n >>= 1)
#pragma unroll
                for (int q = 0; q < n; ++q) {
                    const bool a = cw[2 * q] >= cw[2 * q + 1];
                    cw[q] = a ? cw[2 * q] : cw[2 * q + 1];
                    ci[q] = a ? ci[2 * q] : ci[2 * q + 1];
                }
            score = cw[0];
            hist[t][j] = (unsigned char)ci[0];

            e_cur = e_next; m_cur = m_next;
        }
        for (; t < TT; ++t) hist[t][j] = (unsigned char)j;   // identity tail

        score += endv;
        // one-time first-index argmax over 64 lanes (serial readlane is fine here)
        float bm = -__builtin_inff();
        int bt = 0;
#pragma unroll
        for (int i = 0; i < KK; ++i) {
            const float si = __uint_as_float(
                __builtin_amdgcn_readlane(__float_as_uint(score), i));
            if (si > bm) { bm = si; bt = i; }
        }
        if (j == 0) bt_sh = bt;
    }

    __syncthreads();   // hist + bt_sh complete; waves 1-3 join here

    // Phase A: all-hypothesis segment replay; wave w -> segments 2w, 2w+1
#pragma unroll
    for (int ss = 0; ss < 2; ++ss) {
        const int s = w * 2 + ss;
        int tag = j;
        if (s == 7) {
            hypo[7][63][j] = (unsigned char)j;            // tag at t=511
            for (int t = TT - 1; t >= 7 * 64 + 1; --t) {
                tag = hist[t][tag];
                hypo[7][t - 1 - 7 * 64][j] = (unsigned char)tag;
            }
        } else {
            for (int t = (s + 1) * 64; t >= s * 64 + 1; --t) {
                tag = hist[t][tag];
                hypo[s][t - 1 - s * 64][j] = (unsigned char)tag;
            }
        }
    }
    __syncthreads();

    // Phase B: compose boundary tags (uniform; broadcast LDS reads)
    const int bt = bt_sh;
    int rows_[8];
    rows_[7] = bt;
#pragma unroll
    for (int s = 6; s >= 0; --s) rows_[s] = hypo[s + 1][0][rows_[s + 1]];

    // Phase C: emit; wave w -> segments 2w, 2w+1; lane j -> time 64s+j
    float* pb = pred + (size_t)b * TT;
#pragma unroll
    for (int ss = 0; ss < 2; ++ss) {
        const int s = w * 2 + ss;
        pb[s * 64 + j] = (float)hypo[s][j][rows_[s]];
    }
}

extern "C" void kernel_launch(void* const* d_in, const int* in_sizes, int n_in,
                              void* d_out, int out_size, void* d_ws, size_t ws_size,
                              hipStream_t stream) {
    const float* X      = (const float*)d_in[0];
    const void*  mask   = d_in[1];
    const float* W      = (const float*)d_in[2];
    const float* bias   = (const float*)d_in[3];
    const float* startT = (const float*)d_in[4];
    const float* endT   = (const float*)d_in[5];
    const float* trans  = (const float*)d_in[6];

    float* em   = (float*)d_out;
    float* pred = (float*)d_out + (size_t)BB * TT * KK;

    emission_kernel<<<(BB * TT) / BM, 256, 0, stream>>>(X, W, bias, em);
    viterbi_kernel<<<BB, 256, 0, stream>>>(em, mask, startT, endT, trans, pred);
}

// Round 8
// 408.315 us; speedup vs baseline: 2.8176x; 2.8176x over previous
//
#include <hip/hip_runtime.h>
#include <hip/hip_bf16.h>

#define BB 64
#define TT 512
#define FF 1024
#define KK 64

typedef unsigned char uchar;

// ---------------- Emission GEMM (round-1 version, measured ~83-88us, 4x) ----------------
#define BM 64
#define BF 64
#define LDA 68

__global__ __launch_bounds__(256)
void emission_kernel(const float* __restrict__ X, const float* __restrict__ W,
                     const float* __restrict__ bias, float* __restrict__ em)
{
    __shared__ float As[BF][LDA];
    __shared__ float Bs[BF][LDA];
    const int tid = threadIdx.x;
    const int row0 = blockIdx.x * BM;
    const int tm = tid & 15;
    const int tn = tid >> 4;
    const int lq = tid & 15;
    const int lr = tid >> 4;

    float acc[4][4];
#pragma unroll
    for (int i = 0; i < 4; ++i)
#pragma unroll
        for (int jj = 0; jj < 4; ++jj) acc[i][jj] = 0.f;

    for (int f0 = 0; f0 < FF; f0 += BF) {
#pragma unroll
        for (int p = 0; p < 4; ++p) {
            const int r = p * 16 + lr;
            float4 a = *(const float4*)(X + (size_t)(row0 + r) * FF + f0 + lq * 4);
            As[lq * 4 + 0][r] = a.x;
            As[lq * 4 + 1][r] = a.y;
            As[lq * 4 + 2][r] = a.z;
            As[lq * 4 + 3][r] = a.w;
            float4 w = *(const float4*)(W + (size_t)r * FF + f0 + lq * 4);
            Bs[lq * 4 + 0][r] = w.x;
            Bs[lq * 4 + 1][r] = w.y;
            Bs[lq * 4 + 2][r] = w.z;
            Bs[lq * 4 + 3][r] = w.w;
        }
        __syncthreads();
#pragma unroll
        for (int f = 0; f < BF; ++f) {
            float4 a = *(const float4*)&As[f][tm * 4];
            float4 b = *(const float4*)&Bs[f][tn * 4];
            acc[0][0] += a.x * b.x; acc[0][1] += a.x * b.y; acc[0][2] += a.x * b.z; acc[0][3] += a.x * b.w;
            acc[1][0] += a.y * b.x; acc[1][1] += a.y * b.y; acc[1][2] += a.y * b.z; acc[1][3] += a.y * b.w;
            acc[2][0] += a.z * b.x; acc[2][1] += a.z * b.y; acc[2][2] += a.z * b.z; acc[2][3] += a.z * b.w;
            acc[3][0] += a.w * b.x; acc[3][1] += a.w * b.y; acc[3][2] += a.w * b.z; acc[3][3] += a.w * b.w;
        }
        __syncthreads();
    }

    const float4 b4 = *(const float4*)(bias + tn * 4);
#pragma unroll
    for (int i = 0; i < 4; ++i) {
        float4 o;
        o.x = acc[i][0] + b4.x;
        o.y = acc[i][1] + b4.y;
        o.z = acc[i][2] + b4.z;
        o.w = acc[i][3] + b4.w;
        *(float4*)(em + (size_t)(row0 + tm * 4 + i) * KK + tn * 4) = o;
    }
}

// ---------------- Forward: VALUE-ONLY recurrence, 1 wave per sequence ----------------
// s_t[j] = fl( max_i fl(s_{t-1}[i] + tc[i][j]) + e_t[j] )  — bit-exact equal to
// reference's max_i fl(fl(s+tc)+e) by monotonicity of float rounding.
// No argmax indices -> no cmp/cndmask chains, small live set (tc[64]+~12 regs)
// fits the 88-VGPR budget with no scratch spills (r3-r7 post-mortem).
__global__ __launch_bounds__(64)
void viterbi_fwd(const float* __restrict__ em, const void* __restrict__ maskp,
                 const float* __restrict__ startT, const float* __restrict__ endT,
                 const float* __restrict__ trans, float* __restrict__ shist,
                 int* __restrict__ btarr)
{
    const int b = blockIdx.x;
    const int j = threadIdx.x;

    const uchar* m8 = (const uchar*)maskp;
    const int* m32 = (const int*)maskp;
    const bool u8m = (m8[1] != 0);

    float tc[KK];
#pragma unroll
    for (int i = 0; i < KK; ++i) tc[i] = trans[i * KK + j];

    const float* emb = em + (size_t)b * TT * KK;
    float* sb = shist + (size_t)b * TT * KK;

    float score = startT[j] + emb[j];   // t = 0
    sb[j] = score;
    const float endv = endT[j];

    float e_cur = emb[KK + j];
    int   m_cur = u8m ? (int)m8[b * TT + 1] : m32[b * TT + 1];

    int t = 1;
    for (; t < TT; ++t) {
        const int tn2 = (t + 1 < TT) ? (t + 1) : (TT - 1);
        const float e_next = emb[(size_t)tn2 * KK + j];
        const int   m_next = u8m ? (int)m8[b * TT + tn2] : m32[b * TT + tn2];

        if (!m_cur) break;   // monotone length mask (validated r1-r7)

        float m;
#pragma unroll
        for (int c = 0; c < 8; ++c) {
            const float v0 = __uint_as_float(__builtin_amdgcn_readlane(__float_as_uint(score), c * 8 + 0)) + tc[c * 8 + 0];
            const float v1 = __uint_as_float(__builtin_amdgcn_readlane(__float_as_uint(score), c * 8 + 1)) + tc[c * 8 + 1];
            const float v2 = __uint_as_float(__builtin_amdgcn_readlane(__float_as_uint(score), c * 8 + 2)) + tc[c * 8 + 2];
            const float v3 = __uint_as_float(__builtin_amdgcn_readlane(__float_as_uint(score), c * 8 + 3)) + tc[c * 8 + 3];
            const float v4 = __uint_as_float(__builtin_amdgcn_readlane(__float_as_uint(score), c * 8 + 4)) + tc[c * 8 + 4];
            const float v5 = __uint_as_float(__builtin_amdgcn_readlane(__float_as_uint(score), c * 8 + 5)) + tc[c * 8 + 5];
            const float v6 = __uint_as_float(__builtin_amdgcn_readlane(__float_as_uint(score), c * 8 + 6)) + tc[c * 8 + 6];
            const float v7 = __uint_as_float(__builtin_amdgcn_readlane(__float_as_uint(score), c * 8 + 7)) + tc[c * 8 + 7];
            const float w = fmaxf(fmaxf(fmaxf(v0, v1), fmaxf(v2, v3)),
                                  fmaxf(fmaxf(v4, v5), fmaxf(v6, v7)));
            m = (c == 0) ? w : fmaxf(m, w);
        }
        score = m + e_cur;                       // e added AFTER max: bit-exact
        sb[(size_t)t * KK + j] = score;

        e_cur = e_next; m_cur = m_next;
    }

    score += endv;
    // one-time first-index argmax over lanes
    float bm = -__builtin_inff();
    int bt = 0;
#pragma unroll
    for (int i = 0; i < KK; ++i) {
        const float si = __uint_as_float(__builtin_amdgcn_readlane(__float_as_uint(score), i));
        if (si > bm) { bm = si; bt = i; }
    }
    if (j == 0) btarr[b] = bt;
}

// ---------------- hist recompute: massively parallel, TLP hides chain latency ----------------
// hist[b][t][j] = first-argmax_i fl(fl(s_{t-1}[i]+trans[i][j]) + e_t[j]), elementwise
// identical to reference (strict > chain). Masked t -> identity j.
// Block = (b, 8 consecutive t), 256 threads = 64 j x 4 t-slots x 2 halves.
__global__ __launch_bounds__(256)
void hist_kernel(const float* __restrict__ em, const void* __restrict__ maskp,
                 const float* __restrict__ trans, const float* __restrict__ shist,
                 uchar* __restrict__ histg)
{
    const int tid = threadIdx.x;
    const int bid = blockIdx.x;
    const int b = bid >> 6;
    const int t0 = (bid & 63) * 8;

    __shared__ float tl[64][65];    // padded trans
    __shared__ float srow[8][64];   // s rows t0-1 .. t0+6

    const uchar* m8 = (const uchar*)maskp;
    const int* m32 = (const int*)maskp;
    const bool u8m = (m8[1] != 0);

#pragma unroll
    for (int p = 0; p < 16; ++p) {
        const int idx = p * 256 + tid;
        tl[idx >> 6][idx & 63] = trans[idx];
    }
#pragma unroll
    for (int p = 0; p < 2; ++p) {
        const int idx = p * 256 + tid;
        const int r = idx >> 6, i2 = idx & 63;
        const int ts = t0 - 1 + r;
        srow[r][i2] = (ts >= 0) ? shist[((size_t)b * TT + ts) * KK + i2] : 0.f;
    }
    __syncthreads();

    const int j = tid & 63;
    const int tq = tid >> 6;

#pragma unroll
    for (int half = 0; half < 2; ++half) {
        const int toff = tq * 2 + half;     // 0..7
        const int t = t0 + toff;
        if (t == 0) continue;               // hist[0] unused
        const int mt = u8m ? (int)m8[b * TT + t] : m32[b * TT + t];
        uchar hv;
        if (!mt) {
            hv = (uchar)j;
        } else {
            const float e = em[((size_t)b * TT + t) * KK + j];
            const float* sr = &srow[toff][0];   // s_{t-1}
            float bm = -__builtin_inff();
            int bi = 0;
#pragma unroll 16
            for (int i = 0; i < KK; ++i) {
                const float cand = (sr[i] + tl[i][j]) + e;   // reference order
                if (cand > bm) { bm = cand; bi = i; }        // strict >: first index
            }
            hv = (uchar)bi;
        }
        histg[((size_t)b * TT + t) * KK + j] = hv;
    }
}

// ---------------- Backtrack: stage hist to LDS + validated segment replay ----------------
__global__ __launch_bounds__(256)
void viterbi_bt(const uchar* __restrict__ histg, const int* __restrict__ btarr,
                float* __restrict__ pred)
{
    const int b = blockIdx.x;
    const int tid = threadIdx.x;
    const int w = tid >> 6;
    const int j = tid & 63;

    __shared__ uchar hist[TT][KK];     // 32 KB
    __shared__ uchar hypo[8][64][64];  // 32 KB

    // stage hist[b] 32 KB coalesced
    const uint4* src = (const uint4*)(histg + (size_t)b * TT * KK);
    uint4* dst = (uint4*)&hist[0][0];
#pragma unroll
    for (int p = 0; p < 8; ++p) dst[p * 256 + tid] = src[p * 256 + tid];
    __syncthreads();

    const int bt = btarr[b];

    // Phase A: all-hypothesis segment replay; wave w -> segments 2w, 2w+1
#pragma unroll
    for (int ss = 0; ss < 2; ++ss) {
        const int s = w * 2 + ss;
        int tag = j;
        if (s == 7) {
            hypo[7][63][j] = (uchar)j;
            for (int t = TT - 1; t >= 7 * 64 + 1; --t) {
                tag = hist[t][tag];
                hypo[7][t - 1 - 7 * 64][j] = (uchar)tag;
            }
        } else {
            for (int t = (s + 1) * 64; t >= s * 64 + 1; --t) {
                tag = hist[t][tag];
                hypo[s][t - 1 - s * 64][j] = (uchar)tag;
            }
        }
    }
    __syncthreads();

    // Phase B: compose boundary tags
    int rows_[8];
    rows_[7] = bt;
#pragma unroll
    for (int s = 6; s >= 0; --s) rows_[s] = hypo[s + 1][0][rows_[s + 1]];

    // Phase C: emit
    float* pb = pred + (size_t)b * TT;
#pragma unroll
    for (int ss = 0; ss < 2; ++ss) {
        const int s = w * 2 + ss;
        pb[s * 64 + j] = (float)hypo[s][j][rows_[s]];
    }
}

// ---------------- Fallback monolithic viterbi (round-6, proven, ~460us) ----------------
__global__ __launch_bounds__(256)
void viterbi_kernel(const float* __restrict__ em, const void* __restrict__ maskp,
                    const float* __restrict__ startT, const float* __restrict__ endT,
                    const float* __restrict__ trans, float* __restrict__ pred)
{
    const int b = blockIdx.x;
    const int tid = threadIdx.x;
    const int w = tid >> 6;
    const int j = tid & 63;

    __shared__ uchar hist[TT][KK];
    __shared__ uchar hypo[8][64][64];
    __shared__ int bt_sh;

    const uchar* m8 = (const uchar*)maskp;
    const int* m32 = (const int*)maskp;
    const bool u8m = (m8[1] != 0);

    if (w == 0) {
        float tc[KK];
#pragma unroll
        for (int i = 0; i < KK; ++i) tc[i] = trans[i * KK + j];

        const float* emb = em + (size_t)b * TT * KK;
        float score = startT[j] + emb[j];
        const float endv = endT[j];

        float e_cur = emb[KK + j];
        int   m_cur = u8m ? (int)m8[b * TT + 1] : m32[b * TT + 1];

        int t = 1;
        for (; t < TT; ++t) {
            const int tn2 = (t + 1 < TT) ? (t + 1) : (TT - 1);
            const float e_next = emb[(size_t)tn2 * KK + j];
            const int   m_next = u8m ? (int)m8[b * TT + tn2] : m32[b * TT + tn2];
            if (!m_cur) break;
            float m = -__builtin_inff();
            int idx = 0;
#pragma unroll
            for (int i = 0; i < KK; ++i) {
                const float si = __uint_as_float(__builtin_amdgcn_readlane(__float_as_uint(score), i));
                const float v = (si + tc[i]) + e_cur;
                if (v > m) { m = v; idx = i; }
            }
            score = m;
            hist[t][j] = (uchar)idx;
            e_cur = e_next; m_cur = m_next;
        }
        for (; t < TT; ++t) hist[t][j] = (uchar)j;

        score += endv;
        float bm = -__builtin_inff();
        int bt = 0;
#pragma unroll
        for (int i = 0; i < KK; ++i) {
            const float si = __uint_as_float(__builtin_amdgcn_readlane(__float_as_uint(score), i));
            if (si > bm) { bm = si; bt = i; }
        }
        if (j == 0) bt_sh = bt;
    }
    __syncthreads();

#pragma unroll
    for (int ss = 0; ss < 2; ++ss) {
        const int s = w * 2 + ss;
        int tag = j;
        if (s == 7) {
            hypo[7][63][j] = (uchar)j;
            for (int t = TT - 1; t >= 7 * 64 + 1; --t) {
                tag = hist[t][tag];
                hypo[7][t - 1 - 7 * 64][j] = (uchar)tag;
            }
        } else {
            for (int t = (s + 1) * 64; t >= s * 64 + 1; --t) {
                tag = hist[t][tag];
                hypo[s][t - 1 - s * 64][j] = (uchar)tag;
            }
        }
    }
    __syncthreads();

    const int bt = bt_sh;
    int rows_[8];
    rows_[7] = bt;
#pragma unroll
    for (int s = 6; s >= 0; --s) rows_[s] = hypo[s + 1][0][rows_[s + 1]];

    float* pb = pred + (size_t)b * TT;
#pragma unroll
    for (int ss = 0; ss < 2; ++ss) {
        const int s = w * 2 + ss;
        pb[s * 64 + j] = (float)hypo[s][j][rows_[s]];
    }
}

extern "C" void kernel_launch(void* const* d_in, const int* in_sizes, int n_in,
                              void* d_out, int out_size, void* d_ws, size_t ws_size,
                              hipStream_t stream) {
    const float* X      = (const float*)d_in[0];
    const void*  mask   = d_in[1];
    const float* W      = (const float*)d_in[2];
    const float* bias   = (const float*)d_in[3];
    const float* startT = (const float*)d_in[4];
    const float* endT   = (const float*)d_in[5];
    const float* trans  = (const float*)d_in[6];

    float* em   = (float*)d_out;
    float* pred = (float*)d_out + (size_t)BB * TT * KK;

    emission_kernel<<<(BB * TT) / BM, 256, 0, stream>>>(X, W, bias, em);

    const size_t SH_BYTES = (size_t)BB * TT * KK * sizeof(float);   // 8 MB
    const size_t HI_BYTES = (size_t)BB * TT * KK;                   // 2 MB
    const size_t NEED = SH_BYTES + HI_BYTES + 256;

    if (ws_size >= NEED) {
        float* shist = (float*)d_ws;
        uchar* histg = (uchar*)d_ws + SH_BYTES;
        int*   btarr = (int*)((uchar*)d_ws + SH_BYTES + HI_BYTES);
        viterbi_fwd<<<BB, 64, 0, stream>>>(em, mask, startT, endT, trans, shist, btarr);
        hist_kernel<<<BB * 64, 256, 0, stream>>>(em, mask, trans, shist, histg);
        viterbi_bt<<<BB, 256, 0, stream>>>(histg, btarr, pred);
    } else {
        viterbi_kernel<<<BB, 256, 0, stream>>>(em, mask, startT, endT, trans, pred);
    }
}

// Round 9
// 284.322 us; speedup vs baseline: 4.0464x; 1.4361x over previous
//
#include <hip/hip_runtime.h>
#include <hip/hip_bf16.h>

#define BB 64
#define TT 512
#define FF 1024
#define KK 64

typedef unsigned char uchar;

// ---------------- Emission GEMM (round-1 version, measured ~83-88us, 5x) ----------------
#define BM 64
#define BF 64
#define LDA 68

__global__ __launch_bounds__(256)
void emission_kernel(const float* __restrict__ X, const float* __restrict__ W,
                     const float* __restrict__ bias, float* __restrict__ em)
{
    __shared__ float As[BF][LDA];
    __shared__ float Bs[BF][LDA];
    const int tid = threadIdx.x;
    const int row0 = blockIdx.x * BM;
    const int tm = tid & 15;
    const int tn = tid >> 4;
    const int lq = tid & 15;
    const int lr = tid >> 4;

    float acc[4][4];
#pragma unroll
    for (int i = 0; i < 4; ++i)
#pragma unroll
        for (int jj = 0; jj < 4; ++jj) acc[i][jj] = 0.f;

    for (int f0 = 0; f0 < FF; f0 += BF) {
#pragma unroll
        for (int p = 0; p < 4; ++p) {
            const int r = p * 16 + lr;
            float4 a = *(const float4*)(X + (size_t)(row0 + r) * FF + f0 + lq * 4);
            As[lq * 4 + 0][r] = a.x;
            As[lq * 4 + 1][r] = a.y;
            As[lq * 4 + 2][r] = a.z;
            As[lq * 4 + 3][r] = a.w;
            float4 w = *(const float4*)(W + (size_t)r * FF + f0 + lq * 4);
            Bs[lq * 4 + 0][r] = w.x;
            Bs[lq * 4 + 1][r] = w.y;
            Bs[lq * 4 + 2][r] = w.z;
            Bs[lq * 4 + 3][r] = w.w;
        }
        __syncthreads();
#pragma unroll
        for (int f = 0; f < BF; ++f) {
            float4 a = *(const float4*)&As[f][tm * 4];
            float4 b = *(const float4*)&Bs[f][tn * 4];
            acc[0][0] += a.x * b.x; acc[0][1] += a.x * b.y; acc[0][2] += a.x * b.z; acc[0][3] += a.x * b.w;
            acc[1][0] += a.y * b.x; acc[1][1] += a.y * b.y; acc[1][2] += a.y * b.z; acc[1][3] += a.y * b.w;
            acc[2][0] += a.z * b.x; acc[2][1] += a.z * b.y; acc[2][2] += a.z * b.z; acc[2][3] += a.z * b.w;
            acc[3][0] += a.w * b.x; acc[3][1] += a.w * b.y; acc[3][2] += a.w * b.z; acc[3][3] += a.w * b.w;
        }
        __syncthreads();
    }

    const float4 b4 = *(const float4*)(bias + tn * 4);
#pragma unroll
    for (int i = 0; i < 4; ++i) {
        float4 o;
        o.x = acc[i][0] + b4.x;
        o.y = acc[i][1] + b4.y;
        o.z = acc[i][2] + b4.z;
        o.w = acc[i][3] + b4.w;
        *(float4*)(em + (size_t)(row0 + tm * 4 + i) * KK + tn * 4) = o;
    }
}

// ---------------- Forward: value-only recurrence, 1 wave/seq ----------------
// launch_bounds(64,1): allocator budget up to 512 VGPR -> tc[64] register-
// resident (r8's VGPR=44 proved it was being re-loaded from L1 every step).
// Length precomputed once (monotone mask) -> no mask loads in loop.
// e prefetch distance 4 via named slots in an unroll-4 body.
#define RLANE(I) __uint_as_float((unsigned)__builtin_amdgcn_readlane((int)__float_as_uint(score), (I)))

#define VSTEP(EV, TIDX) do {                                                   \
    float m_;                                                                  \
    _Pragma("unroll")                                                          \
    for (int c = 0; c < 8; ++c) {                                              \
        const float v0 = RLANE(c * 8 + 0) + tc[c * 8 + 0];                     \
        const float v1 = RLANE(c * 8 + 1) + tc[c * 8 + 1];                     \
        const float v2 = RLANE(c * 8 + 2) + tc[c * 8 + 2];                     \
        const float v3 = RLANE(c * 8 + 3) + tc[c * 8 + 3];                     \
        const float v4 = RLANE(c * 8 + 4) + tc[c * 8 + 4];                     \
        const float v5 = RLANE(c * 8 + 5) + tc[c * 8 + 5];                     \
        const float v6 = RLANE(c * 8 + 6) + tc[c * 8 + 6];                     \
        const float v7 = RLANE(c * 8 + 7) + tc[c * 8 + 7];                     \
        const float w_ = fmaxf(fmaxf(fmaxf(v0, v1), fmaxf(v2, v3)),           \
                               fmaxf(fmaxf(v4, v5), fmaxf(v6, v7)));           \
        m_ = (c == 0) ? w_ : fmaxf(m_, w_);                                    \
    }                                                                          \
    score = m_ + (EV);                                                         \
    sb[(size_t)(TIDX) * KK + j] = score;                                       \
} while (0)

__global__ __launch_bounds__(64, 1)
void viterbi_fwd(const float* __restrict__ em, const void* __restrict__ maskp,
                 const float* __restrict__ startT, const float* __restrict__ endT,
                 const float* __restrict__ trans, float* __restrict__ shist,
                 int* __restrict__ btarr)
{
    const int b = blockIdx.x;
    const int j = threadIdx.x;

    const uchar* m8 = (const uchar*)maskp;
    const int* m32 = (const int*)maskp;
    const bool u8m = (m8[1] != 0);

    // ---- length precompute (mask is monotone: true for t < len) ----
    int myc;
    if (u8m) {
        const uint2 mv = *(const uint2*)(m8 + (size_t)b * TT + j * 8);
        const unsigned s4 = (mv.x & 0x01010101u) + (mv.y & 0x01010101u);
        myc = (int)((s4 * 0x01010101u) >> 24);
    } else {
        const int* mp = m32 + (size_t)b * TT + j * 8;
        const int4 a = *(const int4*)mp;
        const int4 c = *(const int4*)(mp + 4);
        myc = (a.x != 0) + (a.y != 0) + (a.z != 0) + (a.w != 0)
            + (c.x != 0) + (c.y != 0) + (c.z != 0) + (c.w != 0);
    }
#pragma unroll
    for (int o = 1; o < 64; o <<= 1) myc += __shfl_xor(myc, o, 64);
    const int len = myc;   // number of valid timesteps; loop runs t = 1..len-1

    float tc[KK];
#pragma unroll
    for (int i = 0; i < KK; ++i) tc[i] = trans[i * KK + j];

    const float* emb = em + (size_t)b * TT * KK;
    float* sb = shist + (size_t)b * TT * KK;

    float score = startT[j] + emb[j];   // t = 0
    sb[j] = score;

    // named prefetch slots: eA..eD hold e for t, t+1, t+2, t+3
    float eA = emb[1 * KK + j];
    float eB = emb[2 * KK + j];
    float eC = emb[3 * KK + j];
    float eD = emb[4 * KK + j];

    int t = 1;
    for (; t + 3 < len; t += 4) {
        VSTEP(eA, t);     eA = emb[(size_t)((t + 4 < TT) ? t + 4 : TT - 1) * KK + j];
        VSTEP(eB, t + 1); eB = emb[(size_t)((t + 5 < TT) ? t + 5 : TT - 1) * KK + j];
        VSTEP(eC, t + 2); eC = emb[(size_t)((t + 6 < TT) ? t + 6 : TT - 1) * KK + j];
        VSTEP(eD, t + 3); eD = emb[(size_t)((t + 7 < TT) ? t + 7 : TT - 1) * KK + j];
    }
    for (; t < len; ++t) {   // tail 0-3 steps
        VSTEP(eA, t);
        eA = eB; eB = eC; eC = eD;
    }

    score += endT[j];
    // one-time first-index argmax over lanes
    float bm = -__builtin_inff();
    int bt = 0;
#pragma unroll
    for (int i = 0; i < KK; ++i) {
        const float si = RLANE(i);
        if (si > bm) { bm = si; bt = i; }
    }
    if (j == 0) btarr[b] = bt;
}

// ---------------- hist recompute: massively parallel (validated r8) ----------------
__global__ __launch_bounds__(256)
void hist_kernel(const float* __restrict__ em, const void* __restrict__ maskp,
                 const float* __restrict__ trans, const float* __restrict__ shist,
                 uchar* __restrict__ histg)
{
    const int tid = threadIdx.x;
    const int bid = blockIdx.x;
    const int b = bid >> 6;
    const int t0 = (bid & 63) * 8;

    __shared__ float tl[64][65];
    __shared__ float srow[8][64];

    const uchar* m8 = (const uchar*)maskp;
    const int* m32 = (const int*)maskp;
    const bool u8m = (m8[1] != 0);

#pragma unroll
    for (int p = 0; p < 16; ++p) {
        const int idx = p * 256 + tid;
        tl[idx >> 6][idx & 63] = trans[idx];
    }
#pragma unroll
    for (int p = 0; p < 2; ++p) {
        const int idx = p * 256 + tid;
        const int r = idx >> 6, i2 = idx & 63;
        const int ts = t0 - 1 + r;
        srow[r][i2] = (ts >= 0) ? shist[((size_t)b * TT + ts) * KK + i2] : 0.f;
    }
    __syncthreads();

    const int j = tid & 63;
    const int tq = tid >> 6;

#pragma unroll
    for (int half = 0; half < 2; ++half) {
        const int toff = tq * 2 + half;
        const int t = t0 + toff;
        if (t == 0) continue;
        const int mt = u8m ? (int)m8[b * TT + t] : m32[b * TT + t];
        uchar hv;
        if (!mt) {
            hv = (uchar)j;
        } else {
            const float e = em[((size_t)b * TT + t) * KK + j];
            const float* sr = &srow[toff][0];
            float bm = -__builtin_inff();
            int bi = 0;
#pragma unroll 16
            for (int i = 0; i < KK; ++i) {
                const float cand = (sr[i] + tl[i][j]) + e;   // reference order
                if (cand > bm) { bm = cand; bi = i; }        // strict >: first index
            }
            hv = (uchar)bi;
        }
        histg[((size_t)b * TT + t) * KK + j] = hv;
    }
}

// ---------------- Backtrack (validated r8) ----------------
__global__ __launch_bounds__(256)
void viterbi_bt(const uchar* __restrict__ histg, const int* __restrict__ btarr,
                float* __restrict__ pred)
{
    const int b = blockIdx.x;
    const int tid = threadIdx.x;
    const int w = tid >> 6;
    const int j = tid & 63;

    __shared__ uchar hist[TT][KK];
    __shared__ uchar hypo[8][64][64];

    const uint4* src = (const uint4*)(histg + (size_t)b * TT * KK);
    uint4* dst = (uint4*)&hist[0][0];
#pragma unroll
    for (int p = 0; p < 8; ++p) dst[p * 256 + tid] = src[p * 256 + tid];
    __syncthreads();

    const int bt = btarr[b];

#pragma unroll
    for (int ss = 0; ss < 2; ++ss) {
        const int s = w * 2 + ss;
        int tag = j;
        if (s == 7) {
            hypo[7][63][j] = (uchar)j;
            for (int t = TT - 1; t >= 7 * 64 + 1; --t) {
                tag = hist[t][tag];
                hypo[7][t - 1 - 7 * 64][j] = (uchar)tag;
            }
        } else {
            for (int t = (s + 1) * 64; t >= s * 64 + 1; --t) {
                tag = hist[t][tag];
                hypo[s][t - 1 - s * 64][j] = (uchar)tag;
            }
        }
    }
    __syncthreads();

    int rows_[8];
    rows_[7] = bt;
#pragma unroll
    for (int s = 6; s >= 0; --s) rows_[s] = hypo[s + 1][0][rows_[s + 1]];

    float* pb = pred + (size_t)b * TT;
#pragma unroll
    for (int ss = 0; ss < 2; ++ss) {
        const int s = w * 2 + ss;
        pb[s * 64 + j] = (float)hypo[s][j][rows_[s]];
    }
}

// ---------------- Fallback monolithic viterbi (round-6, proven) ----------------
__global__ __launch_bounds__(256)
void viterbi_kernel(const float* __restrict__ em, const void* __restrict__ maskp,
                    const float* __restrict__ startT, const float* __restrict__ endT,
                    const float* __restrict__ trans, float* __restrict__ pred)
{
    const int b = blockIdx.x;
    const int tid = threadIdx.x;
    const int w = tid >> 6;
    const int j = tid & 63;

    __shared__ uchar hist[TT][KK];
    __shared__ uchar hypo[8][64][64];
    __shared__ int bt_sh;

    const uchar* m8 = (const uchar*)maskp;
    const int* m32 = (const int*)maskp;
    const bool u8m = (m8[1] != 0);

    if (w == 0) {
        float tc[KK];
#pragma unroll
        for (int i = 0; i < KK; ++i) tc[i] = trans[i * KK + j];

        const float* emb = em + (size_t)b * TT * KK;
        float score = startT[j] + emb[j];
        const float endv = endT[j];

        float e_cur = emb[KK + j];
        int   m_cur = u8m ? (int)m8[b * TT + 1] : m32[b * TT + 1];

        int t = 1;
        for (; t < TT; ++t) {
            const int tn2 = (t + 1 < TT) ? (t + 1) : (TT - 1);
            const float e_next = emb[(size_t)tn2 * KK + j];
            const int   m_next = u8m ? (int)m8[b * TT + tn2] : m32[b * TT + tn2];
            if (!m_cur) break;
            float m = -__builtin_inff();
            int idx = 0;
#pragma unroll
            for (int i = 0; i < KK; ++i) {
                const float si = __uint_as_float(__builtin_amdgcn_readlane(__float_as_uint(score), i));
                const float v = (si + tc[i]) + e_cur;
                if (v > m) { m = v; idx = i; }
            }
            score = m;
            hist[t][j] = (uchar)idx;
            e_cur = e_next; m_cur = m_next;
        }
        for (; t < TT; ++t) hist[t][j] = (uchar)j;

        score += endv;
        float bm = -__builtin_inff();
        int bt = 0;
#pragma unroll
        for (int i = 0; i < KK; ++i) {
            const float si = __uint_as_float(__builtin_amdgcn_readlane(__float_as_uint(score), i));
            if (si > bm) { bm = si; bt = i; }
        }
        if (j == 0) bt_sh = bt;
    }
    __syncthreads();

#pragma unroll
    for (int ss = 0; ss < 2; ++ss) {
        const int s = w * 2 + ss;
        int tag = j;
        if (s == 7) {
            hypo[7][63][j] = (uchar)j;
            for (int t = TT - 1; t >= 7 * 64 + 1; --t) {
                tag = hist[t][tag];
                hypo[7][t - 1 - 7 * 64][j] = (uchar)tag;
            }
        } else {
            for (int t = (s + 1) * 64; t >= s * 64 + 1; --t) {
                tag = hist[t][tag];
                hypo[s][t - 1 - s * 64][j] = (uchar)tag;
            }
        }
    }
    __syncthreads();

    const int bt = bt_sh;
    int rows_[8];
    rows_[7] = bt;
#pragma unroll
    for (int s = 6; s >= 0; --s) rows_[s] = hypo[s + 1][0][rows_[s + 1]];

    float* pb = pred + (size_t)b * TT;
#pragma unroll
    for (int ss = 0; ss < 2; ++ss) {
        const int s = w * 2 + ss;
        pb[s * 64 + j] = (float)hypo[s][j][rows_[s]];
    }
}

extern "C" void kernel_launch(void* const* d_in, const int* in_sizes, int n_in,
                              void* d_out, int out_size, void* d_ws, size_t ws_size,
                              hipStream_t stream) {
    const float* X      = (const float*)d_in[0];
    const void*  mask   = d_in[1];
    const float* W      = (const float*)d_in[2];
    const float* bias   = (const float*)d_in[3];
    const float* startT = (const float*)d_in[4];
    const float* endT   = (const float*)d_in[5];
    const float* trans  = (const float*)d_in[6];

    float* em   = (float*)d_out;
    float* pred = (float*)d_out + (size_t)BB * TT * KK;

    emission_kernel<<<(BB * TT) / BM, 256, 0, stream>>>(X, W, bias, em);

    const size_t SH_BYTES = (size_t)BB * TT * KK * sizeof(float);   // 8 MB
    const size_t HI_BYTES = (size_t)BB * TT * KK;                   // 2 MB
    const size_t NEED = SH_BYTES + HI_BYTES + 256;

    if (ws_size >= NEED) {
        float* shist = (float*)d_ws;
        uchar* histg = (uchar*)d_ws + SH_BYTES;
        int*   btarr = (int*)((uchar*)d_ws + SH_BYTES + HI_BYTES);
        viterbi_fwd<<<BB, 64, 0, stream>>>(em, mask, startT, endT, trans, shist, btarr);
        hist_kernel<<<BB * 64, 256, 0, stream>>>(em, mask, trans, shist, histg);
        viterbi_bt<<<BB, 256, 0, stream>>>(histg, btarr, pred);
    } else {
        viterbi_kernel<<<BB, 256, 0, stream>>>(em, mask, startT, endT, trans, pred);
    }
}

// Round 10
// 269.887 us; speedup vs baseline: 4.2628x; 1.0535x over previous
//
#include <hip/hip_runtime.h>
#include <hip/hip_bf16.h>

#define BB 64
#define TT 512
#define FF 1024
#define KK 64

typedef unsigned char uchar;

// ---------------- Emission GEMM (round-1 version, measured ~83-88us, 5x) ----------------
#define BM 64
#define BF 64
#define LDA 68

__global__ __launch_bounds__(256)
void emission_kernel(const float* __restrict__ X, const float* __restrict__ W,
                     const float* __restrict__ bias, float* __restrict__ em)
{
    __shared__ float As[BF][LDA];
    __shared__ float Bs[BF][LDA];
    const int tid = threadIdx.x;
    const int row0 = blockIdx.x * BM;
    const int tm = tid & 15;
    const int tn = tid >> 4;
    const int lq = tid & 15;
    const int lr = tid >> 4;

    float acc[4][4];
#pragma unroll
    for (int i = 0; i < 4; ++i)
#pragma unroll
        for (int jj = 0; jj < 4; ++jj) acc[i][jj] = 0.f;

    for (int f0 = 0; f0 < FF; f0 += BF) {
#pragma unroll
        for (int p = 0; p < 4; ++p) {
            const int r = p * 16 + lr;
            float4 a = *(const float4*)(X + (size_t)(row0 + r) * FF + f0 + lq * 4);
            As[lq * 4 + 0][r] = a.x;
            As[lq * 4 + 1][r] = a.y;
            As[lq * 4 + 2][r] = a.z;
            As[lq * 4 + 3][r] = a.w;
            float4 w = *(const float4*)(W + (size_t)r * FF + f0 + lq * 4);
            Bs[lq * 4 + 0][r] = w.x;
            Bs[lq * 4 + 1][r] = w.y;
            Bs[lq * 4 + 2][r] = w.z;
            Bs[lq * 4 + 3][r] = w.w;
        }
        __syncthreads();
#pragma unroll
        for (int f = 0; f < BF; ++f) {
            float4 a = *(const float4*)&As[f][tm * 4];
            float4 b = *(const float4*)&Bs[f][tn * 4];
            acc[0][0] += a.x * b.x; acc[0][1] += a.x * b.y; acc[0][2] += a.x * b.z; acc[0][3] += a.x * b.w;
            acc[1][0] += a.y * b.x; acc[1][1] += a.y * b.y; acc[1][2] += a.y * b.z; acc[1][3] += a.y * b.w;
            acc[2][0] += a.z * b.x; acc[2][1] += a.z * b.y; acc[2][2] += a.z * b.z; acc[2][3] += a.z * b.w;
            acc[3][0] += a.w * b.x; acc[3][1] += a.w * b.y; acc[3][2] += a.w * b.z; acc[3][3] += a.w * b.w;
        }
        __syncthreads();
    }

    const float4 b4 = *(const float4*)(bias + tn * 4);
#pragma unroll
    for (int i = 0; i < 4; ++i) {
        float4 o;
        o.x = acc[i][0] + b4.x;
        o.y = acc[i][1] + b4.y;
        o.z = acc[i][2] + b4.z;
        o.w = acc[i][3] + b4.w;
        *(float4*)(em + (size_t)(row0 + tm * 4 + i) * KK + tn * 4) = o;
    }
}

// ---------------- Forward: value-only recurrence, 1 wave/seq ----------------
// r9 post-mortem: VGPR=52 proved tc[64] was STILL reloaded in-loop despite
// launch_bounds(64,1). Fix: asm volatile "+v" pin after the loads — the asm
// result is opaque, so the loads cannot be rematerialized; tc must stay in
// VGPRs. Also: 3-ary fmaxf groups -> v_max3_f32 (exact: fmax never rounds).
#define RLANE(I) __uint_as_float((unsigned)__builtin_amdgcn_readlane((int)__float_as_uint(score), (I)))

#define VSTEP(EV, TIDX) do {                                                   \
    float m_;                                                                  \
    _Pragma("unroll")                                                          \
    for (int c = 0; c < 8; ++c) {                                              \
        const float v0 = RLANE(c * 8 + 0) + tc[c * 8 + 0];                     \
        const float v1 = RLANE(c * 8 + 1) + tc[c * 8 + 1];                     \
        const float v2 = RLANE(c * 8 + 2) + tc[c * 8 + 2];                     \
        const float v3 = RLANE(c * 8 + 3) + tc[c * 8 + 3];                     \
        const float v4 = RLANE(c * 8 + 4) + tc[c * 8 + 4];                     \
        const float v5 = RLANE(c * 8 + 5) + tc[c * 8 + 5];                     \
        const float v6 = RLANE(c * 8 + 6) + tc[c * 8 + 6];                     \
        const float v7 = RLANE(c * 8 + 7) + tc[c * 8 + 7];                     \
        const float ma = fmaxf(fmaxf(v0, v1), v2);   /* v_max3 */              \
        const float mb = fmaxf(fmaxf(v3, v4), v5);   /* v_max3 */              \
        const float mc = fmaxf(fmaxf(v6, v7), ma);   /* v_max3 */              \
        const float w_ = fmaxf(mb, mc);                                        \
        m_ = (c == 0) ? w_ : fmaxf(m_, w_);                                    \
    }                                                                          \
    score = m_ + (EV);                                                         \
    sb[(size_t)(TIDX) * KK + j] = score;                                       \
} while (0)

__global__ __launch_bounds__(64, 1)
void viterbi_fwd(const float* __restrict__ em, const void* __restrict__ maskp,
                 const float* __restrict__ startT, const float* __restrict__ endT,
                 const float* __restrict__ trans, float* __restrict__ shist,
                 int* __restrict__ btarr)
{
    const int b = blockIdx.x;
    const int j = threadIdx.x;

    const uchar* m8 = (const uchar*)maskp;
    const int* m32 = (const int*)maskp;
    const bool u8m = (m8[1] != 0);

    // ---- length precompute (mask is monotone: true for t < len) ----
    int myc;
    if (u8m) {
        const uint2 mv = *(const uint2*)(m8 + (size_t)b * TT + j * 8);
        const unsigned s4 = (mv.x & 0x01010101u) + (mv.y & 0x01010101u);
        myc = (int)((s4 * 0x01010101u) >> 24);
    } else {
        const int* mp = m32 + (size_t)b * TT + j * 8;
        const int4 a = *(const int4*)mp;
        const int4 c = *(const int4*)(mp + 4);
        myc = (a.x != 0) + (a.y != 0) + (a.z != 0) + (a.w != 0)
            + (c.x != 0) + (c.y != 0) + (c.z != 0) + (c.w != 0);
    }
#pragma unroll
    for (int o = 1; o < 64; o <<= 1) myc += __shfl_xor(myc, o, 64);
    const int len = myc;   // valid timesteps; loop runs t = 1..len-1

    float tc[KK];
#pragma unroll
    for (int i = 0; i < KK; ++i) tc[i] = trans[i * KK + j];
    // PIN: opaque asm result -> loads cannot be rematerialized in-loop
#pragma unroll
    for (int i = 0; i < KK; ++i) asm volatile("" : "+v"(tc[i]));

    const float* emb = em + (size_t)b * TT * KK;
    float* sb = shist + (size_t)b * TT * KK;

    float score = startT[j] + emb[j];   // t = 0
    sb[j] = score;

    // named prefetch slots: eA..eD hold e for t, t+1, t+2, t+3
    float eA = emb[1 * KK + j];
    float eB = emb[2 * KK + j];
    float eC = emb[3 * KK + j];
    float eD = emb[4 * KK + j];

    int t = 1;
    for (; t + 3 < len; t += 4) {
        VSTEP(eA, t);     eA = emb[(size_t)((t + 4 < TT) ? t + 4 : TT - 1) * KK + j];
        VSTEP(eB, t + 1); eB = emb[(size_t)((t + 5 < TT) ? t + 5 : TT - 1) * KK + j];
        VSTEP(eC, t + 2); eC = emb[(size_t)((t + 6 < TT) ? t + 6 : TT - 1) * KK + j];
        VSTEP(eD, t + 3); eD = emb[(size_t)((t + 7 < TT) ? t + 7 : TT - 1) * KK + j];
    }
    for (; t < len; ++t) {   // tail 0-3 steps
        VSTEP(eA, t);
        eA = eB; eB = eC; eC = eD;
    }

    score += endT[j];
    // one-time first-index argmax over lanes
    float bm = -__builtin_inff();
    int bt = 0;
#pragma unroll
    for (int i = 0; i < KK; ++i) {
        const float si = RLANE(i);
        if (si > bm) { bm = si; bt = i; }
    }
    if (j == 0) btarr[b] = bt;
}

// ---------------- hist recompute: massively parallel (validated r8-r9) ----------------
__global__ __launch_bounds__(256)
void hist_kernel(const float* __restrict__ em, const void* __restrict__ maskp,
                 const float* __restrict__ trans, const float* __restrict__ shist,
                 uchar* __restrict__ histg)
{
    const int tid = threadIdx.x;
    const int bid = blockIdx.x;
    const int b = bid >> 6;
    const int t0 = (bid & 63) * 8;

    __shared__ float tl[64][65];
    __shared__ float srow[8][64];

    const uchar* m8 = (const uchar*)maskp;
    const int* m32 = (const int*)maskp;
    const bool u8m = (m8[1] != 0);

#pragma unroll
    for (int p = 0; p < 16; ++p) {
        const int idx = p * 256 + tid;
        tl[idx >> 6][idx & 63] = trans[idx];
    }
#pragma unroll
    for (int p = 0; p < 2; ++p) {
        const int idx = p * 256 + tid;
        const int r = idx >> 6, i2 = idx & 63;
        const int ts = t0 - 1 + r;
        srow[r][i2] = (ts >= 0) ? shist[((size_t)b * TT + ts) * KK + i2] : 0.f;
    }
    __syncthreads();

    const int j = tid & 63;
    const int tq = tid >> 6;

#pragma unroll
    for (int half = 0; half < 2; ++half) {
        const int toff = tq * 2 + half;
        const int t = t0 + toff;
        if (t == 0) continue;
        const int mt = u8m ? (int)m8[b * TT + t] : m32[b * TT + t];
        uchar hv;
        if (!mt) {
            hv = (uchar)j;
        } else {
            const float e = em[((size_t)b * TT + t) * KK + j];
            const float* sr = &srow[toff][0];
            float bm = -__builtin_inff();
            int bi = 0;
#pragma unroll 16
            for (int i = 0; i < KK; ++i) {
                const float cand = (sr[i] + tl[i][j]) + e;   // reference order
                if (cand > bm) { bm = cand; bi = i; }        // strict >: first index
            }
            hv = (uchar)bi;
        }
        histg[((size_t)b * TT + t) * KK + j] = hv;
    }
}

// ---------------- Backtrack (validated r8-r9) ----------------
__global__ __launch_bounds__(256)
void viterbi_bt(const uchar* __restrict__ histg, const int* __restrict__ btarr,
                float* __restrict__ pred)
{
    const int b = blockIdx.x;
    const int tid = threadIdx.x;
    const int w = tid >> 6;
    const int j = tid & 63;

    __shared__ uchar hist[TT][KK];
    __shared__ uchar hypo[8][64][64];

    const uint4* src = (const uint4*)(histg + (size_t)b * TT * KK);
    uint4* dst = (uint4*)&hist[0][0];
#pragma unroll
    for (int p = 0; p < 8; ++p) dst[p * 256 + tid] = src[p * 256 + tid];
    __syncthreads();

    const int bt = btarr[b];

#pragma unroll
    for (int ss = 0; ss < 2; ++ss) {
        const int s = w * 2 + ss;
        int tag = j;
        if (s == 7) {
            hypo[7][63][j] = (uchar)j;
            for (int t = TT - 1; t >= 7 * 64 + 1; --t) {
                tag = hist[t][tag];
                hypo[7][t - 1 - 7 * 64][j] = (uchar)tag;
            }
        } else {
            for (int t = (s + 1) * 64; t >= s * 64 + 1; --t) {
                tag = hist[t][tag];
                hypo[s][t - 1 - s * 64][j] = (uchar)tag;
            }
        }
    }
    __syncthreads();

    int rows_[8];
    rows_[7] = bt;
#pragma unroll
    for (int s = 6; s >= 0; --s) rows_[s] = hypo[s + 1][0][rows_[s + 1]];

    float* pb = pred + (size_t)b * TT;
#pragma unroll
    for (int ss = 0; ss < 2; ++ss) {
        const int s = w * 2 + ss;
        pb[s * 64 + j] = (float)hypo[s][j][rows_[s]];
    }
}

// ---------------- Fallback monolithic viterbi (round-6, proven) ----------------
__global__ __launch_bounds__(256)
void viterbi_kernel(const float* __restrict__ em, const void* __restrict__ maskp,
                    const float* __restrict__ startT, const float* __restrict__ endT,
                    const float* __restrict__ trans, float* __restrict__ pred)
{
    const int b = blockIdx.x;
    const int tid = threadIdx.x;
    const int w = tid >> 6;
    const int j = tid & 63;

    __shared__ uchar hist[TT][KK];
    __shared__ uchar hypo[8][64][64];
    __shared__ int bt_sh;

    const uchar* m8 = (const uchar*)maskp;
    const int* m32 = (const int*)maskp;
    const bool u8m = (m8[1] != 0);

    if (w == 0) {
        float tc[KK];
#pragma unroll
        for (int i = 0; i < KK; ++i) tc[i] = trans[i * KK + j];

        const float* emb = em + (size_t)b * TT * KK;
        float score = startT[j] + emb[j];
        const float endv = endT[j];

        float e_cur = emb[KK + j];
        int   m_cur = u8m ? (int)m8[b * TT + 1] : m32[b * TT + 1];

        int t = 1;
        for (; t < TT; ++t) {
            const int tn2 = (t + 1 < TT) ? (t + 1) : (TT - 1);
            const float e_next = emb[(size_t)tn2 * KK + j];
            const int   m_next = u8m ? (int)m8[b * TT + tn2] : m32[b * TT + tn2];
            if (!m_cur) break;
            float m = -__builtin_inff();
            int idx = 0;
#pragma unroll
            for (int i = 0; i < KK; ++i) {
                const float si = __uint_as_float(__builtin_amdgcn_readlane(__float_as_uint(score), i));
                const float v = (si + tc[i]) + e_cur;
                if (v > m) { m = v; idx = i; }
            }
            score = m;
            hist[t][j] = (uchar)idx;
            e_cur = e_next; m_cur = m_next;
        }
        for (; t < TT; ++t) hist[t][j] = (uchar)j;

        score += endv;
        float bm = -__builtin_inff();
        int bt = 0;
#pragma unroll
        for (int i = 0; i < KK; ++i) {
            const float si = __uint_as_float(__builtin_amdgcn_readlane(__float_as_uint(score), i));
            if (si > bm) { bm = si; bt = i; }
        }
        if (j == 0) bt_sh = bt;
    }
    __syncthreads();

#pragma unroll
    for (int ss = 0; ss < 2; ++ss) {
        const int s = w * 2 + ss;
        int tag = j;
        if (s == 7) {
            hypo[7][63][j] = (uchar)j;
            for (int t = TT - 1; t >= 7 * 64 + 1; --t) {
                tag = hist[t][tag];
                hypo[7][t - 1 - 7 * 64][j] = (uchar)tag;
            }
        } else {
            for (int t = (s + 1) * 64; t >= s * 64 + 1; --t) {
                tag = hist[t][tag];
                hypo[s][t - 1 - s * 64][j] = (uchar)tag;
            }
        }
    }
    __syncthreads();

    const int bt = bt_sh;
    int rows_[8];
    rows_[7] = bt;
#pragma unroll
    for (int s = 6; s >= 0; --s) rows_[s] = hypo[s + 1][0][rows_[s + 1]];

    float* pb = pred + (size_t)b * TT;
#pragma unroll
    for (int ss = 0; ss < 2; ++ss) {
        const int s = w * 2 + ss;
        pb[s * 64 + j] = (float)hypo[s][j][rows_[s]];
    }
}

extern "C" void kernel_launch(void* const* d_in, const int* in_sizes, int n_in,
                              void* d_out, int out_size, void* d_ws, size_t ws_size,
                              hipStream_t stream) {
    const float* X      = (const float*)d_in[0];
    const void*  mask   = d_in[1];
    const float* W      = (const float*)d_in[2];
    const float* bias   = (const float*)d_in[3];
    const float* startT = (const float*)d_in[4];
    const float* endT   = (const float*)d_in[5];
    const float* trans  = (const float*)d_in[6];

    float* em   = (float*)d_out;
    float* pred = (float*)d_out + (size_t)BB * TT * KK;

    emission_kernel<<<(BB * TT) / BM, 256, 0, stream>>>(X, W, bias, em);

    const size_t SH_BYTES = (size_t)BB * TT * KK * sizeof(float);   // 8 MB
    const size_t HI_BYTES = (size_t)BB * TT * KK;                   // 2 MB
    const size_t NEED = SH_BYTES + HI_BYTES + 256;

    if (ws_size >= NEED) {
        float* shist = (float*)d_ws;
        uchar* histg = (uchar*)d_ws + SH_BYTES;
        int*   btarr = (int*)((uchar*)d_ws + SH_BYTES + HI_BYTES);
        viterbi_fwd<<<BB, 64, 0, stream>>>(em, mask, startT, endT, trans, shist, btarr);
        hist_kernel<<<BB * 64, 256, 0, stream>>>(em, mask, trans, shist, histg);
        viterbi_bt<<<BB, 256, 0, stream>>>(histg, btarr, pred);
    } else {
        viterbi_kernel<<<BB, 256, 0, stream>>>(em, mask, startT, endT, trans, pred);
    }
}